// Round 2
// baseline (1962.483 us; speedup 1.0000x reference)
//
#include <hip/hip_runtime.h>
#include <math.h>

#define B_ 4
#define T_ 2048
#define C_ 1024
#define H_ 16
#define D_ 64
#define M_ (B_ * T_) // 8192

// ---------------------------------------------------------------------------
// GEMM: Y = A[M,1024] @ W[1024,N] + bias[N]
//   MODE 0: plain row-major write  out[m*N + n]
//   MODE 1: QKV head-scatter write out[((b*H + h)*T + t)*D + d], n = h*64+d
// Tile: 128x128, BK=8, 256 threads, 8x8 micro-tile per thread.
// ---------------------------------------------------------------------------
template <int MODE>
__global__ __launch_bounds__(256) void gemm128(const float* __restrict__ A,
                                               const float* __restrict__ W,
                                               const float* __restrict__ bias,
                                               float* __restrict__ out,
                                               int N) {
  __shared__ float As[8][128]; // As[k][m] (transposed)
  __shared__ float Bs[8][128]; // Bs[k][n]

  const int tid = threadIdx.x;
  const int m0 = blockIdx.y * 128;
  const int n0 = blockIdx.x * 128;

  const int rb = (tid >> 4) * 8; // micro-tile row base (0..120)
  const int cb = (tid & 15) * 8; // micro-tile col base (0..120)

  // global->LDS load roles
  const int ar = tid >> 1;        // A row 0..127
  const int ac = (tid & 1) * 4;   // A col offset 0 or 4
  const int br = tid >> 5;        // B row 0..7
  const int bc = (tid & 31) * 4;  // B col offset 0..124

  float acc[8][8];
#pragma unroll
  for (int i = 0; i < 8; ++i)
#pragma unroll
    for (int j = 0; j < 8; ++j) acc[i][j] = 0.0f;

  for (int k0 = 0; k0 < C_; k0 += 8) {
    const float4 av = *(const float4*)&A[(size_t)(m0 + ar) * C_ + k0 + ac];
    const float4 bv = *(const float4*)&W[(size_t)(k0 + br) * N + n0 + bc];
    __syncthreads(); // previous iteration's compute done before overwrite
    As[ac + 0][ar] = av.x;
    As[ac + 1][ar] = av.y;
    As[ac + 2][ar] = av.z;
    As[ac + 3][ar] = av.w;
    *(float4*)&Bs[br][bc] = bv;
    __syncthreads();
#pragma unroll
    for (int kk = 0; kk < 8; ++kk) {
      float a[8], b[8];
      *(float4*)&a[0] = *(const float4*)&As[kk][rb];
      *(float4*)&a[4] = *(const float4*)&As[kk][rb + 4];
      *(float4*)&b[0] = *(const float4*)&Bs[kk][cb];
      *(float4*)&b[4] = *(const float4*)&Bs[kk][cb + 4];
#pragma unroll
      for (int i = 0; i < 8; ++i)
#pragma unroll
        for (int j = 0; j < 8; ++j) acc[i][j] = fmaf(a[i], b[j], acc[i][j]);
    }
  }

#pragma unroll
  for (int i = 0; i < 8; ++i) {
    const int m = m0 + rb + i;
    const int b = m >> 11;     // T_ = 2048
    const int t = m & 2047;
#pragma unroll
    for (int j = 0; j < 8; j += 4) {
      const int n = n0 + cb + j;
      float4 r;
      r.x = acc[i][j + 0] + bias[n + 0];
      r.y = acc[i][j + 1] + bias[n + 1];
      r.z = acc[i][j + 2] + bias[n + 2];
      r.w = acc[i][j + 3] + bias[n + 3];
      if (MODE == 0) {
        *(float4*)&out[(size_t)m * N + n] = r;
      } else {
        const int h = n >> 6;
        const int d = n & 63;
        *(float4*)&out[(((size_t)b * H_ + h) * T_ + t) * D_ + d] = r;
      }
    }
  }
}

// ---------------------------------------------------------------------------
// Flash attention (non-causal), fp32.
// grid: (T/64, B*H), 256 threads. Per block: 64 Q rows of one head.
// Each thread: 4x4 logits micro-tile and 4x4 output micro-tile.
// ---------------------------------------------------------------------------
__global__ __launch_bounds__(256) void flash_attn(const float* __restrict__ Q,
                                                  const float* __restrict__ K,
                                                  const float* __restrict__ V,
                                                  float* __restrict__ ctx) {
  __shared__ float QsT[64][68]; // QsT[d][r]
  __shared__ float KsT[64][68]; // KsT[d][c]
  __shared__ float Vs[64][68];  // Vs[s][d]
  __shared__ float Ps[64][68];  // Ps[s][r]

  const int tid = threadIdx.x;
  const int bh = blockIdx.y; // b*H + h
  const int q0 = blockIdx.x * 64;
  const size_t base = (size_t)bh * T_ * D_;

  const int tx = tid & 15, ty = tid >> 4;
  const int rb = ty * 4; // q-row base within tile
  const int cb = tx * 4; // col base (s for QK^T, d for PV)

  // staging roles: 4 threads per row, 16 cols each
  const int sr = tid >> 2;
  const int sc = (tid & 3) * 16;

  // ---- stage Q (transposed) ----
  {
    const float* qp = Q + base + (size_t)(q0 + sr) * D_ + sc;
    const float4 v0 = *(const float4*)(qp + 0);
    const float4 v1 = *(const float4*)(qp + 4);
    const float4 v2 = *(const float4*)(qp + 8);
    const float4 v3 = *(const float4*)(qp + 12);
    QsT[sc + 0][sr] = v0.x; QsT[sc + 1][sr] = v0.y;
    QsT[sc + 2][sr] = v0.z; QsT[sc + 3][sr] = v0.w;
    QsT[sc + 4][sr] = v1.x; QsT[sc + 5][sr] = v1.y;
    QsT[sc + 6][sr] = v1.z; QsT[sc + 7][sr] = v1.w;
    QsT[sc + 8][sr] = v2.x; QsT[sc + 9][sr] = v2.y;
    QsT[sc + 10][sr] = v2.z; QsT[sc + 11][sr] = v2.w;
    QsT[sc + 12][sr] = v3.x; QsT[sc + 13][sr] = v3.y;
    QsT[sc + 14][sr] = v3.z; QsT[sc + 15][sr] = v3.w;
  }

  float o[4][4];
  float mrow[4], lrow[4];
#pragma unroll
  for (int i = 0; i < 4; ++i) {
    mrow[i] = -1e30f;
    lrow[i] = 0.0f;
#pragma unroll
    for (int j = 0; j < 4; ++j) o[i][j] = 0.0f;
  }

  for (int s0 = 0; s0 < T_; s0 += 64) {
    __syncthreads(); // previous tile's reads of KsT/Vs complete
    // ---- stage K (transposed) and V ----
    {
      const float* kp = K + base + (size_t)(s0 + sr) * D_ + sc;
      const float4 v0 = *(const float4*)(kp + 0);
      const float4 v1 = *(const float4*)(kp + 4);
      const float4 v2 = *(const float4*)(kp + 8);
      const float4 v3 = *(const float4*)(kp + 12);
      KsT[sc + 0][sr] = v0.x; KsT[sc + 1][sr] = v0.y;
      KsT[sc + 2][sr] = v0.z; KsT[sc + 3][sr] = v0.w;
      KsT[sc + 4][sr] = v1.x; KsT[sc + 5][sr] = v1.y;
      KsT[sc + 6][sr] = v1.z; KsT[sc + 7][sr] = v1.w;
      KsT[sc + 8][sr] = v2.x; KsT[sc + 9][sr] = v2.y;
      KsT[sc + 10][sr] = v2.z; KsT[sc + 11][sr] = v2.w;
      KsT[sc + 12][sr] = v3.x; KsT[sc + 13][sr] = v3.y;
      KsT[sc + 14][sr] = v3.z; KsT[sc + 15][sr] = v3.w;
      const float* vp = V + base + (size_t)(s0 + sr) * D_ + sc;
      const float4 w0 = *(const float4*)(vp + 0);
      const float4 w1 = *(const float4*)(vp + 4);
      const float4 w2 = *(const float4*)(vp + 8);
      const float4 w3 = *(const float4*)(vp + 12);
      *(float4*)&Vs[sr][sc + 0] = w0;
      *(float4*)&Vs[sr][sc + 4] = w1;
      *(float4*)&Vs[sr][sc + 8] = w2;
      *(float4*)&Vs[sr][sc + 12] = w3;
    }
    __syncthreads();

    // ---- S = (Q K^T) * 1/sqrt(D) ----
    float s[4][4];
#pragma unroll
    for (int i = 0; i < 4; ++i)
#pragma unroll
      for (int j = 0; j < 4; ++j) s[i][j] = 0.0f;

    for (int d = 0; d < 64; ++d) {
      const float4 qv = *(const float4*)&QsT[d][rb];
      const float4 kv = *(const float4*)&KsT[d][cb];
      const float qa[4] = {qv.x, qv.y, qv.z, qv.w};
      const float ka[4] = {kv.x, kv.y, kv.z, kv.w};
#pragma unroll
      for (int i = 0; i < 4; ++i)
#pragma unroll
        for (int j = 0; j < 4; ++j) s[i][j] = fmaf(qa[i], ka[j], s[i][j]);
    }

    // ---- online softmax update (per q row, 16-lane tx group) ----
#pragma unroll
    for (int i = 0; i < 4; ++i) {
      float mx = s[i][0] * 0.125f;
#pragma unroll
      for (int j = 0; j < 4; ++j) {
        s[i][j] *= 0.125f;
        mx = fmaxf(mx, s[i][j]);
      }
#pragma unroll
      for (int off = 1; off < 16; off <<= 1)
        mx = fmaxf(mx, __shfl_xor(mx, off));
      const float newm = fmaxf(mrow[i], mx);
      const float corr = __expf(mrow[i] - newm);
      mrow[i] = newm;
      float rs = 0.0f;
#pragma unroll
      for (int j = 0; j < 4; ++j) {
        const float p = __expf(s[i][j] - newm);
        s[i][j] = p;
        rs += p;
      }
#pragma unroll
      for (int off = 1; off < 16; off <<= 1) rs += __shfl_xor(rs, off);
      lrow[i] = lrow[i] * corr + rs;
#pragma unroll
      for (int j = 0; j < 4; ++j) o[i][j] *= corr;
    }

    // ---- write P transposed: Ps[s][r] ----
#pragma unroll
    for (int i = 0; i < 4; ++i)
#pragma unroll
      for (int j = 0; j < 4; ++j) Ps[cb + j][rb + i] = s[i][j];
    __syncthreads();

    // ---- O += P V ----
    for (int ss = 0; ss < 64; ++ss) {
      const float4 pv = *(const float4*)&Ps[ss][rb];
      const float4 vv = *(const float4*)&Vs[ss][cb];
      const float pa[4] = {pv.x, pv.y, pv.z, pv.w};
      const float va[4] = {vv.x, vv.y, vv.z, vv.w};
#pragma unroll
      for (int i = 0; i < 4; ++i)
#pragma unroll
        for (int j = 0; j < 4; ++j) o[i][j] = fmaf(pa[i], va[j], o[i][j]);
    }
  }

  // ---- epilogue: normalize, write ctx[b, t, h*64 + d] ----
  const int b = bh >> 4; // H_ = 16
  const int h = bh & 15;
#pragma unroll
  for (int i = 0; i < 4; ++i) {
    const float inv = 1.0f / lrow[i];
    float4 r;
    r.x = o[i][0] * inv;
    r.y = o[i][1] * inv;
    r.z = o[i][2] * inv;
    r.w = o[i][3] * inv;
    *(float4*)&ctx[((size_t)b * T_ + q0 + rb + i) * C_ + h * D_ + cb] = r;
  }
}

// ---------------------------------------------------------------------------
extern "C" void kernel_launch(void* const* d_in, const int* in_sizes, int n_in,
                              void* d_out, int out_size, void* d_ws,
                              size_t ws_size, hipStream_t stream) {
  const float* x = (const float*)d_in[0];
  const float* Wq = (const float*)d_in[1];
  const float* bq = (const float*)d_in[2];
  const float* Wk = (const float*)d_in[3];
  const float* bk = (const float*)d_in[4];
  const float* Wv = (const float*)d_in[5];
  const float* bv = (const float*)d_in[6];
  const float* Wp = (const float*)d_in[7];
  const float* bp = (const float*)d_in[8];
  float* out = (float*)d_out;

  float* Qb = (float*)d_ws;                  // [B,H,T,D]
  float* Kb = Qb + (size_t)M_ * C_;          // [B,H,T,D]
  float* Vb = Kb + (size_t)M_ * C_;          // [B,H,T,D]
  float* Cb = Vb + (size_t)M_ * C_;          // [B,T,C] attention context

  const dim3 blk(256);
  const dim3 gg(C_ / 128, M_ / 128); // 8 x 64

  gemm128<1><<<gg, blk, 0, stream>>>(x, Wq, bq, Qb, C_);
  gemm128<1><<<gg, blk, 0, stream>>>(x, Wk, bk, Kb, C_);
  gemm128<1><<<gg, blk, 0, stream>>>(x, Wv, bv, Vb, C_);

  flash_attn<<<dim3(T_ / 64, B_ * H_), blk, 0, stream>>>(Qb, Kb, Vb, Cb);

  gemm128<0><<<gg, blk, 0, stream>>>(Cb, Wp, bp, out, C_);

  (void)in_sizes; (void)n_in; (void)out_size; (void)ws_size;
}

// Round 3
// 1397.775 us; speedup vs baseline: 1.4040x; 1.4040x over previous
//
#include <hip/hip_runtime.h>
#include <math.h>

#define B_ 4
#define T_ 2048
#define C_ 1024
#define H_ 16
#define D_ 64
#define M_ (B_ * T_) // 8192

using bf16x8 = __attribute__((ext_vector_type(8))) short;
using f32x4  = __attribute__((ext_vector_type(4))) float;

__device__ __forceinline__ unsigned short f2bf(float f) {
  unsigned u = __float_as_uint(f);
  unsigned r = u + 0x7FFFu + ((u >> 16) & 1u); // RNE
  return (unsigned short)(r >> 16);
}
__device__ __forceinline__ float bf2f(unsigned short h) {
  return __uint_as_float(((unsigned)h) << 16);
}

// ---------------------------------------------------------------------------
// conv_x: split fp32 -> bf16 hi/lo, elementwise. n divisible by 4*256.
// ---------------------------------------------------------------------------
__global__ __launch_bounds__(256) void conv_x(const float* __restrict__ x,
                                              unsigned short* __restrict__ hi,
                                              unsigned short* __restrict__ lo) {
  const size_t i = ((size_t)blockIdx.x * 256 + threadIdx.x) * 4;
  const float4 v = *(const float4*)&x[i];
  ushort4 h, l;
  h.x = f2bf(v.x); l.x = f2bf(v.x - bf2f(h.x));
  h.y = f2bf(v.y); l.y = f2bf(v.y - bf2f(h.y));
  h.z = f2bf(v.z); l.z = f2bf(v.z - bf2f(h.z));
  h.w = f2bf(v.w); l.w = f2bf(v.w - bf2f(h.w));
  *(ushort4*)&hi[i] = h;
  *(ushort4*)&lo[i] = l;
}

// ---------------------------------------------------------------------------
// conv_wT: W[1024][1024] fp32 -> transposed split bf16 dst[n_off+n][k].
// 64x64 tiles via LDS.
// ---------------------------------------------------------------------------
__global__ __launch_bounds__(256) void conv_wT(const float* __restrict__ W,
                                               unsigned short* __restrict__ hi,
                                               unsigned short* __restrict__ lo,
                                               int n_off) {
  __shared__ float t[64][65];
  const int k0 = blockIdx.y * 64, n0 = blockIdx.x * 64;
  const int lr = threadIdx.x >> 4;        // 0..15
  const int lc4 = (threadIdx.x & 15) * 4; // 0..60
#pragma unroll
  for (int i = 0; i < 4; ++i) {
    const int r = lr + 16 * i;
    const float4 v = *(const float4*)&W[(size_t)(k0 + r) * 1024 + n0 + lc4];
    t[r][lc4 + 0] = v.x; t[r][lc4 + 1] = v.y;
    t[r][lc4 + 2] = v.z; t[r][lc4 + 3] = v.w;
  }
  __syncthreads();
#pragma unroll
  for (int i = 0; i < 4; ++i) {
    const int nr = lr + 16 * i; // n within tile
    ushort4 h, l;
    float a0 = t[lc4 + 0][nr], a1 = t[lc4 + 1][nr];
    float a2 = t[lc4 + 2][nr], a3 = t[lc4 + 3][nr];
    h.x = f2bf(a0); l.x = f2bf(a0 - bf2f(h.x));
    h.y = f2bf(a1); l.y = f2bf(a1 - bf2f(h.y));
    h.z = f2bf(a2); l.z = f2bf(a2 - bf2f(h.z));
    h.w = f2bf(a3); l.w = f2bf(a3 - bf2f(h.w));
    const size_t o = (size_t)(n_off + n0 + nr) * 1024 + k0 + lc4;
    *(ushort4*)&hi[o] = h;
    *(ushort4*)&lo[o] = l;
  }
}

// ---------------------------------------------------------------------------
// Split-bf16 MFMA GEMM: C[M,N] = Ahi.Bhi + Ahi.Blo + Alo.Bhi (+bias).
// A: [8192][1024] bf16 row-major. B: [N][1024] bf16 (transposed weights).
// Tile 128x128, BK=32, 256 threads (4 waves 2x2), mfma_f32_16x16x32_bf16.
// LDS linear with XOR k-chunk swizzle: slot = q ^ ((row>>1)&3), pre-applied
// to the global source address (global_load_lds writes linearly).
//   MODE 0: out[m*1024+n] = v + bias[n]
//   MODE 1: QKV scatter: seg = n>>10 -> Q/K/V [b,h,t,d] with n%1024 = h*64+d
// ---------------------------------------------------------------------------
template <int MODE>
__global__ __launch_bounds__(256) void gemm_mfma(
    const unsigned short* __restrict__ Ahi, const unsigned short* __restrict__ Alo,
    const unsigned short* __restrict__ Bhi, const unsigned short* __restrict__ Blo,
    const float* __restrict__ bias0, const float* __restrict__ bias1,
    const float* __restrict__ bias2,
    float* __restrict__ O0, float* __restrict__ O1, float* __restrict__ O2) {
  __shared__ __align__(16) unsigned short Als[128 * 32];
  __shared__ __align__(16) unsigned short Bls[128 * 32];

  const int tid = threadIdx.x;
  const int lane = tid & 63;
  const int wid = tid >> 6;
  const int m0 = blockIdx.y * 128, n0 = blockIdx.x * 128;
  const int wm = (wid >> 1) * 64, wn = (wid & 1) * 64;

  f32x4 acc[4][4] = {};

  const int srow = lane >> 2; // staging row within chunk (0..15)
  const int sc = lane & 3;    // stored k-chunk slot

  for (int k0 = 0; k0 < 3 * 1024; k0 += 32) {
    const int seg = k0 >> 10;
    const int kk = k0 & 1023;
    const unsigned short* ga = (seg == 2) ? Alo : Ahi;
    const unsigned short* gb = (seg == 1) ? Blo : Bhi;

    __syncthreads(); // prior iteration's ds_reads complete before overwrite
#pragma unroll
    for (int c = 0; c < 2; ++c) {
      const int chunk = wid * 2 + c;
      const int row = chunk * 16 + srow;
      const int kch = sc ^ ((row >> 1) & 3); // semantic k-chunk for this slot
      {
        const unsigned short* src = ga + (size_t)(m0 + row) * 1024 + kk + kch * 8;
        __builtin_amdgcn_global_load_lds(
            (const __attribute__((address_space(1))) void*)src,
            (__attribute__((address_space(3))) void*)(Als + chunk * 512), 16, 0, 0);
      }
      {
        const unsigned short* src = gb + (size_t)(n0 + row) * 1024 + kk + kch * 8;
        __builtin_amdgcn_global_load_lds(
            (const __attribute__((address_space(1))) void*)src,
            (__attribute__((address_space(3))) void*)(Bls + chunk * 512), 16, 0, 0);
      }
    }
    __syncthreads(); // vmcnt(0) drained by compiler before barrier

    const int fr = lane & 15;
    const int q = lane >> 4;
    bf16x8 af[4], bfr[4];
#pragma unroll
    for (int i = 0; i < 4; ++i) {
      const int arow = wm + i * 16 + fr;
      af[i] = *(const bf16x8*)(Als + arow * 32 + (q ^ ((arow >> 1) & 3)) * 8);
      const int brow = wn + i * 16 + fr;
      bfr[i] = *(const bf16x8*)(Bls + brow * 32 + (q ^ ((brow >> 1) & 3)) * 8);
    }
#pragma unroll
    for (int i = 0; i < 4; ++i)
#pragma unroll
      for (int j = 0; j < 4; ++j)
        acc[i][j] = __builtin_amdgcn_mfma_f32_16x16x32_bf16(af[i], bfr[j], acc[i][j], 0, 0, 0);
  }

  // epilogue: C row = (lane>>4)*4 + r, col = lane&15 (guide m89/m91 verified)
  const int fr = lane & 15;
  const int q = lane >> 4;
#pragma unroll
  for (int i = 0; i < 4; ++i) {
#pragma unroll
    for (int j = 0; j < 4; ++j) {
#pragma unroll
      for (int r = 0; r < 4; ++r) {
        const int m = m0 + wm + i * 16 + q * 4 + r;
        const int n = n0 + wn + j * 16 + fr;
        const float v = acc[i][j][r];
        if (MODE == 0) {
          O0[(size_t)m * 1024 + n] = v + bias0[n];
        } else {
          const int seg = n >> 10, w = n & 1023, h = w >> 6, d = w & 63;
          const float* bp = (seg == 0) ? bias0 : (seg == 1) ? bias1 : bias2;
          float* dst = (seg == 0) ? O0 : (seg == 1) ? O1 : O2;
          const int b = m >> 11, t = m & 2047;
          dst[(((size_t)b * H_ + h) * T_ + t) * D_ + d] = v + bp[w];
        }
      }
    }
  }
}

// ---------------------------------------------------------------------------
// Flash attention (non-causal), fp32 VALU (unchanged this round except the
// epilogue now emits split-bf16 hi/lo for the out-projection GEMM).
// ---------------------------------------------------------------------------
__global__ __launch_bounds__(256) void flash_attn(const float* __restrict__ Q,
                                                  const float* __restrict__ K,
                                                  const float* __restrict__ V,
                                                  unsigned short* __restrict__ chi,
                                                  unsigned short* __restrict__ clo) {
  __shared__ float QsT[64][68]; // QsT[d][r]
  __shared__ float KsT[64][68]; // KsT[d][c]
  __shared__ float Vs[64][68];  // Vs[s][d]
  __shared__ float Ps[64][68];  // Ps[s][r]

  const int tid = threadIdx.x;
  const int bh = blockIdx.y; // b*H + h
  const int q0 = blockIdx.x * 64;
  const size_t base = (size_t)bh * T_ * D_;

  const int tx = tid & 15, ty = tid >> 4;
  const int rb = ty * 4;
  const int cb = tx * 4;

  const int sr = tid >> 2;
  const int sc = (tid & 3) * 16;

  {
    const float* qp = Q + base + (size_t)(q0 + sr) * D_ + sc;
    const float4 v0 = *(const float4*)(qp + 0);
    const float4 v1 = *(const float4*)(qp + 4);
    const float4 v2 = *(const float4*)(qp + 8);
    const float4 v3 = *(const float4*)(qp + 12);
    QsT[sc + 0][sr] = v0.x; QsT[sc + 1][sr] = v0.y;
    QsT[sc + 2][sr] = v0.z; QsT[sc + 3][sr] = v0.w;
    QsT[sc + 4][sr] = v1.x; QsT[sc + 5][sr] = v1.y;
    QsT[sc + 6][sr] = v1.z; QsT[sc + 7][sr] = v1.w;
    QsT[sc + 8][sr] = v2.x; QsT[sc + 9][sr] = v2.y;
    QsT[sc + 10][sr] = v2.z; QsT[sc + 11][sr] = v2.w;
    QsT[sc + 12][sr] = v3.x; QsT[sc + 13][sr] = v3.y;
    QsT[sc + 14][sr] = v3.z; QsT[sc + 15][sr] = v3.w;
  }

  float o[4][4];
  float mrow[4], lrow[4];
#pragma unroll
  for (int i = 0; i < 4; ++i) {
    mrow[i] = -1e30f;
    lrow[i] = 0.0f;
#pragma unroll
    for (int j = 0; j < 4; ++j) o[i][j] = 0.0f;
  }

  for (int s0 = 0; s0 < T_; s0 += 64) {
    __syncthreads();
    {
      const float* kp = K + base + (size_t)(s0 + sr) * D_ + sc;
      const float4 v0 = *(const float4*)(kp + 0);
      const float4 v1 = *(const float4*)(kp + 4);
      const float4 v2 = *(const float4*)(kp + 8);
      const float4 v3 = *(const float4*)(kp + 12);
      KsT[sc + 0][sr] = v0.x; KsT[sc + 1][sr] = v0.y;
      KsT[sc + 2][sr] = v0.z; KsT[sc + 3][sr] = v0.w;
      KsT[sc + 4][sr] = v1.x; KsT[sc + 5][sr] = v1.y;
      KsT[sc + 6][sr] = v1.z; KsT[sc + 7][sr] = v1.w;
      KsT[sc + 8][sr] = v2.x; KsT[sc + 9][sr] = v2.y;
      KsT[sc + 10][sr] = v2.z; KsT[sc + 11][sr] = v2.w;
      KsT[sc + 12][sr] = v3.x; KsT[sc + 13][sr] = v3.y;
      KsT[sc + 14][sr] = v3.z; KsT[sc + 15][sr] = v3.w;
      const float* vp = V + base + (size_t)(s0 + sr) * D_ + sc;
      const float4 w0 = *(const float4*)(vp + 0);
      const float4 w1 = *(const float4*)(vp + 4);
      const float4 w2 = *(const float4*)(vp + 8);
      const float4 w3 = *(const float4*)(vp + 12);
      *(float4*)&Vs[sr][sc + 0] = w0;
      *(float4*)&Vs[sr][sc + 4] = w1;
      *(float4*)&Vs[sr][sc + 8] = w2;
      *(float4*)&Vs[sr][sc + 12] = w3;
    }
    __syncthreads();

    float s[4][4];
#pragma unroll
    for (int i = 0; i < 4; ++i)
#pragma unroll
      for (int j = 0; j < 4; ++j) s[i][j] = 0.0f;

    for (int d = 0; d < 64; ++d) {
      const float4 qv = *(const float4*)&QsT[d][rb];
      const float4 kv = *(const float4*)&KsT[d][cb];
      const float qa[4] = {qv.x, qv.y, qv.z, qv.w};
      const float ka[4] = {kv.x, kv.y, kv.z, kv.w};
#pragma unroll
      for (int i = 0; i < 4; ++i)
#pragma unroll
        for (int j = 0; j < 4; ++j) s[i][j] = fmaf(qa[i], ka[j], s[i][j]);
    }

#pragma unroll
    for (int i = 0; i < 4; ++i) {
      float mx = s[i][0] * 0.125f;
#pragma unroll
      for (int j = 0; j < 4; ++j) {
        s[i][j] *= 0.125f;
        mx = fmaxf(mx, s[i][j]);
      }
#pragma unroll
      for (int off = 1; off < 16; off <<= 1)
        mx = fmaxf(mx, __shfl_xor(mx, off));
      const float newm = fmaxf(mrow[i], mx);
      const float corr = __expf(mrow[i] - newm);
      mrow[i] = newm;
      float rs = 0.0f;
#pragma unroll
      for (int j = 0; j < 4; ++j) {
        const float p = __expf(s[i][j] - newm);
        s[i][j] = p;
        rs += p;
      }
#pragma unroll
      for (int off = 1; off < 16; off <<= 1) rs += __shfl_xor(rs, off);
      lrow[i] = lrow[i] * corr + rs;
#pragma unroll
      for (int j = 0; j < 4; ++j) o[i][j] *= corr;
    }

#pragma unroll
    for (int i = 0; i < 4; ++i)
#pragma unroll
      for (int j = 0; j < 4; ++j) Ps[cb + j][rb + i] = s[i][j];
    __syncthreads();

    for (int ss = 0; ss < 64; ++ss) {
      const float4 pv = *(const float4*)&Ps[ss][rb];
      const float4 vv = *(const float4*)&Vs[ss][cb];
      const float pa[4] = {pv.x, pv.y, pv.z, pv.w};
      const float va[4] = {vv.x, vv.y, vv.z, vv.w};
#pragma unroll
      for (int i = 0; i < 4; ++i)
#pragma unroll
        for (int j = 0; j < 4; ++j) o[i][j] = fmaf(pa[i], va[j], o[i][j]);
    }
  }

  const int b = bh >> 4;
  const int h = bh & 15;
#pragma unroll
  for (int i = 0; i < 4; ++i) {
    const float inv = 1.0f / lrow[i];
    ushort4 hh, ll;
    float v0 = o[i][0] * inv, v1 = o[i][1] * inv;
    float v2 = o[i][2] * inv, v3 = o[i][3] * inv;
    hh.x = f2bf(v0); ll.x = f2bf(v0 - bf2f(hh.x));
    hh.y = f2bf(v1); ll.y = f2bf(v1 - bf2f(hh.y));
    hh.z = f2bf(v2); ll.z = f2bf(v2 - bf2f(hh.z));
    hh.w = f2bf(v3); ll.w = f2bf(v3 - bf2f(hh.w));
    const size_t idx = ((size_t)b * T_ + q0 + rb + i) * C_ + h * D_ + cb;
    *(ushort4*)&chi[idx] = hh;
    *(ushort4*)&clo[idx] = ll;
  }
}

// ---------------------------------------------------------------------------
extern "C" void kernel_launch(void* const* d_in, const int* in_sizes, int n_in,
                              void* d_out, int out_size, void* d_ws,
                              size_t ws_size, hipStream_t stream) {
  const float* x = (const float*)d_in[0];
  const float* Wq = (const float*)d_in[1];
  const float* bq = (const float*)d_in[2];
  const float* Wk = (const float*)d_in[3];
  const float* bk = (const float*)d_in[4];
  const float* Wv = (const float*)d_in[5];
  const float* bv = (const float*)d_in[6];
  const float* Wp = (const float*)d_in[7];
  const float* bp = (const float*)d_in[8];
  float* out = (float*)d_out;

  // workspace layout (bytes)
  char* w = (char*)d_ws;
  unsigned short* xhi = (unsigned short*)w;                   w += (size_t)M_ * C_ * 2;
  unsigned short* xlo = (unsigned short*)w;                   w += (size_t)M_ * C_ * 2;
  unsigned short* Wqkv_hi = (unsigned short*)w;               w += (size_t)3 * C_ * C_ * 2;
  unsigned short* Wqkv_lo = (unsigned short*)w;               w += (size_t)3 * C_ * C_ * 2;
  unsigned short* Wp_hi = (unsigned short*)w;                 w += (size_t)C_ * C_ * 2;
  unsigned short* Wp_lo = (unsigned short*)w;                 w += (size_t)C_ * C_ * 2;
  float* Qb = (float*)w;                                      w += (size_t)M_ * C_ * 4;
  float* Kb = (float*)w;                                      w += (size_t)M_ * C_ * 4;
  float* Vb = (float*)w;                                      w += (size_t)M_ * C_ * 4;
  unsigned short* chi = (unsigned short*)w;                   w += (size_t)M_ * C_ * 2;
  unsigned short* clo = (unsigned short*)w;                   w += (size_t)M_ * C_ * 2;

  const dim3 blk(256);

  // split x
  conv_x<<<dim3((M_ * C_) / (4 * 256)), blk, 0, stream>>>(x, xhi, xlo);
  // transpose+split weights: [n][k] bf16
  conv_wT<<<dim3(16, 16), blk, 0, stream>>>(Wq, Wqkv_hi, Wqkv_lo, 0);
  conv_wT<<<dim3(16, 16), blk, 0, stream>>>(Wk, Wqkv_hi, Wqkv_lo, 1024);
  conv_wT<<<dim3(16, 16), blk, 0, stream>>>(Wv, Wqkv_hi, Wqkv_lo, 2048);
  conv_wT<<<dim3(16, 16), blk, 0, stream>>>(Wp, Wp_hi, Wp_lo, 0);

  // fused QKV projection: M=8192, N=3072
  gemm_mfma<1><<<dim3(3072 / 128, M_ / 128), blk, 0, stream>>>(
      xhi, xlo, Wqkv_hi, Wqkv_lo, bq, bk, bv, Qb, Kb, Vb);

  flash_attn<<<dim3(T_ / 64, B_ * H_), blk, 0, stream>>>(Qb, Kb, Vb, chi, clo);

  // output projection: M=8192, N=1024
  gemm_mfma<0><<<dim3(1024 / 128, M_ / 128), blk, 0, stream>>>(
      chi, clo, Wp_hi, Wp_lo, bp, bp, bp, out, out, out);

  (void)in_sizes; (void)n_in; (void)out_size; (void)ws_size;
}

// Round 4
// 641.532 us; speedup vs baseline: 3.0591x; 2.1788x over previous
//
#include <hip/hip_runtime.h>
#include <math.h>

#define B_ 4
#define T_ 2048
#define C_ 1024
#define H_ 16
#define D_ 64
#define M_ (B_ * T_) // 8192

using bf16x8 = __attribute__((ext_vector_type(8))) short;
using f32x4  = __attribute__((ext_vector_type(4))) float;

__device__ __forceinline__ unsigned short f2bf(float f) {
  unsigned u = __float_as_uint(f);
  unsigned r = u + 0x7FFFu + ((u >> 16) & 1u); // RNE
  return (unsigned short)(r >> 16);
}
__device__ __forceinline__ float bf2f(unsigned short h) {
  return __uint_as_float(((unsigned)h) << 16);
}

// ---------------------------------------------------------------------------
// conv_x: split fp32 -> bf16 hi/lo, elementwise.
// ---------------------------------------------------------------------------
__global__ __launch_bounds__(256) void conv_x(const float* __restrict__ x,
                                              unsigned short* __restrict__ hi,
                                              unsigned short* __restrict__ lo) {
  const size_t i = ((size_t)blockIdx.x * 256 + threadIdx.x) * 4;
  const float4 v = *(const float4*)&x[i];
  ushort4 h, l;
  h.x = f2bf(v.x); l.x = f2bf(v.x - bf2f(h.x));
  h.y = f2bf(v.y); l.y = f2bf(v.y - bf2f(h.y));
  h.z = f2bf(v.z); l.z = f2bf(v.z - bf2f(h.z));
  h.w = f2bf(v.w); l.w = f2bf(v.w - bf2f(h.w));
  *(ushort4*)&hi[i] = h;
  *(ushort4*)&lo[i] = l;
}

// ---------------------------------------------------------------------------
// conv_wT: W[1024][1024] fp32 -> transposed split bf16 dst[n_off+n][k].
// ---------------------------------------------------------------------------
__global__ __launch_bounds__(256) void conv_wT(const float* __restrict__ W,
                                               unsigned short* __restrict__ hi,
                                               unsigned short* __restrict__ lo,
                                               int n_off) {
  __shared__ float t[64][65];
  const int k0 = blockIdx.y * 64, n0 = blockIdx.x * 64;
  const int lr = threadIdx.x >> 4;
  const int lc4 = (threadIdx.x & 15) * 4;
#pragma unroll
  for (int i = 0; i < 4; ++i) {
    const int r = lr + 16 * i;
    const float4 v = *(const float4*)&W[(size_t)(k0 + r) * 1024 + n0 + lc4];
    t[r][lc4 + 0] = v.x; t[r][lc4 + 1] = v.y;
    t[r][lc4 + 2] = v.z; t[r][lc4 + 3] = v.w;
  }
  __syncthreads();
#pragma unroll
  for (int i = 0; i < 4; ++i) {
    const int nr = lr + 16 * i;
    ushort4 h, l;
    float a0 = t[lc4 + 0][nr], a1 = t[lc4 + 1][nr];
    float a2 = t[lc4 + 2][nr], a3 = t[lc4 + 3][nr];
    h.x = f2bf(a0); l.x = f2bf(a0 - bf2f(h.x));
    h.y = f2bf(a1); l.y = f2bf(a1 - bf2f(h.y));
    h.z = f2bf(a2); l.z = f2bf(a2 - bf2f(h.z));
    h.w = f2bf(a3); l.w = f2bf(a3 - bf2f(h.w));
    const size_t o = (size_t)(n_off + n0 + nr) * 1024 + k0 + lc4;
    *(ushort4*)&hi[o] = h;
    *(ushort4*)&lo[o] = l;
  }
}

// ---------------------------------------------------------------------------
// Split-bf16 MFMA GEMM (128x128 tile, BK=32, 4 waves).
//   MODE 0: P0 = float out[m*1024+n] (+bias0)
//   MODE 1: QKV: P0..P3 = Qhi,Qlo,Khi,Klo as [b,h,t,d] u16;
//           P4,P5 = Vthi,Vtlo as [b,h,d,t] u16 (transposed V).
// ---------------------------------------------------------------------------
template <int MODE>
__global__ __launch_bounds__(256) void gemm_mfma(
    const unsigned short* __restrict__ Ahi, const unsigned short* __restrict__ Alo,
    const unsigned short* __restrict__ Bhi, const unsigned short* __restrict__ Blo,
    const float* __restrict__ bias0, const float* __restrict__ bias1,
    const float* __restrict__ bias2,
    void* P0, void* P1, void* P2, void* P3, void* P4, void* P5) {
  __shared__ __align__(16) unsigned short Als[128 * 32];
  __shared__ __align__(16) unsigned short Bls[128 * 32];

  const int tid = threadIdx.x;
  const int lane = tid & 63;
  const int wid = tid >> 6;
  const int m0 = blockIdx.y * 128, n0 = blockIdx.x * 128;
  const int wm = (wid >> 1) * 64, wn = (wid & 1) * 64;

  f32x4 acc[4][4] = {};

  const int srow = lane >> 2;
  const int sc = lane & 3;

  for (int k0 = 0; k0 < 3 * 1024; k0 += 32) {
    const int seg = k0 >> 10;
    const int kk = k0 & 1023;
    const unsigned short* ga = (seg == 2) ? Alo : Ahi;
    const unsigned short* gb = (seg == 1) ? Blo : Bhi;

    __syncthreads();
#pragma unroll
    for (int c = 0; c < 2; ++c) {
      const int chunk = wid * 2 + c;
      const int row = chunk * 16 + srow;
      const int kch = sc ^ ((row >> 1) & 3);
      {
        const unsigned short* src = ga + (size_t)(m0 + row) * 1024 + kk + kch * 8;
        __builtin_amdgcn_global_load_lds(
            (const __attribute__((address_space(1))) void*)src,
            (__attribute__((address_space(3))) void*)(Als + chunk * 512), 16, 0, 0);
      }
      {
        const unsigned short* src = gb + (size_t)(n0 + row) * 1024 + kk + kch * 8;
        __builtin_amdgcn_global_load_lds(
            (const __attribute__((address_space(1))) void*)src,
            (__attribute__((address_space(3))) void*)(Bls + chunk * 512), 16, 0, 0);
      }
    }
    __syncthreads();

    const int fr = lane & 15;
    const int q = lane >> 4;
    bf16x8 af[4], bfr[4];
#pragma unroll
    for (int i = 0; i < 4; ++i) {
      const int arow = wm + i * 16 + fr;
      af[i] = *(const bf16x8*)(Als + arow * 32 + (q ^ ((arow >> 1) & 3)) * 8);
      const int brow = wn + i * 16 + fr;
      bfr[i] = *(const bf16x8*)(Bls + brow * 32 + (q ^ ((brow >> 1) & 3)) * 8);
    }
#pragma unroll
    for (int i = 0; i < 4; ++i)
#pragma unroll
      for (int j = 0; j < 4; ++j)
        acc[i][j] = __builtin_amdgcn_mfma_f32_16x16x32_bf16(af[i], bfr[j], acc[i][j], 0, 0, 0);
  }

  const int fr = lane & 15;
  const int q = lane >> 4;
  if (MODE == 0) {
    float* out = (float*)P0;
#pragma unroll
    for (int i = 0; i < 4; ++i)
#pragma unroll
      for (int j = 0; j < 4; ++j)
#pragma unroll
        for (int r = 0; r < 4; ++r) {
          const int m = m0 + wm + i * 16 + q * 4 + r;
          const int n = n0 + wn + j * 16 + fr;
          out[(size_t)m * 1024 + n] = acc[i][j][r] + bias0[n];
        }
  } else {
#pragma unroll
    for (int i = 0; i < 4; ++i) {
#pragma unroll
      for (int j = 0; j < 4; ++j) {
        const int n = n0 + wn + j * 16 + fr;
        const int seg = n >> 10, ww = n & 1023, h = ww >> 6, d = ww & 63;
        const float bv = ((seg == 0) ? bias0 : (seg == 1) ? bias1 : bias2)[ww];
        const int mb = m0 + wm + i * 16 + q * 4;
        const int b = mb >> 11, t0 = mb & 2047;
        unsigned short hv[4], lv[4];
#pragma unroll
        for (int r = 0; r < 4; ++r) {
          const float v = acc[i][j][r] + bv;
          hv[r] = f2bf(v);
          lv[r] = f2bf(v - bf2f(hv[r]));
        }
        if (seg == 2) { // V: transposed [b,h,d,t], t contiguous across r
          const size_t o = (((size_t)b * H_ + h) * D_ + d) * T_ + t0;
          ushort4 h4, l4;
          h4.x = hv[0]; h4.y = hv[1]; h4.z = hv[2]; h4.w = hv[3];
          l4.x = lv[0]; l4.y = lv[1]; l4.z = lv[2]; l4.w = lv[3];
          *(ushort4*)&((unsigned short*)P4)[o] = h4;
          *(ushort4*)&((unsigned short*)P5)[o] = l4;
        } else {
          unsigned short* Hq = (unsigned short*)((seg == 0) ? P0 : P2);
          unsigned short* Lq = (unsigned short*)((seg == 0) ? P1 : P3);
          const size_t ob = ((size_t)b * H_ + h) * T_;
#pragma unroll
          for (int r = 0; r < 4; ++r) {
            const size_t o = (ob + t0 + r) * D_ + d;
            Hq[o] = hv[r];
            Lq[o] = lv[r];
          }
        }
      }
    }
  }
}

// ---------------------------------------------------------------------------
// MFMA flash attention (non-causal). Split-bf16 QK^T, bf16 P, split-bf16 V.
// Block: 256 thr (4 waves), QBLK=128 (32 q-rows/wave), KVBLK=64.
// Q in registers; K/Vt staged in LDS via global_load_lds with XOR swizzle;
// P through per-wave padded LDS buffer. Output: split bf16 ctx [b,t,h*64+d].
// ---------------------------------------------------------------------------
__global__ __launch_bounds__(256) void flash_mfma(
    const unsigned short* __restrict__ Qhi, const unsigned short* __restrict__ Qlo,
    const unsigned short* __restrict__ Khi, const unsigned short* __restrict__ Klo,
    const unsigned short* __restrict__ Vthi, const unsigned short* __restrict__ Vtlo,
    unsigned short* __restrict__ chi, unsigned short* __restrict__ clo) {
  __shared__ __align__(16) unsigned short KhiS[64 * 64];
  __shared__ __align__(16) unsigned short KloS[64 * 64];
  __shared__ __align__(16) unsigned short VhiS[64 * 64];
  __shared__ __align__(16) unsigned short VloS[64 * 64];
  __shared__ __align__(16) unsigned short Ps[4][32][80]; // padded: stride 160B

  const int tid = threadIdx.x;
  const int lane = tid & 63;
  const int w = tid >> 6;
  const int bh = blockIdx.y;
  const int b = bh >> 4, h = bh & 15;
  const int q0 = blockIdx.x * 128;
  const int fr = lane & 15, q = lane >> 4;

  const size_t kbase = (size_t)bh * T_ * D_; // shorts, [t][d]
  const size_t vbase = (size_t)bh * D_ * T_; // shorts, [d][t]

  // ---- Q fragments in registers (per wave: rows w*32 .. w*32+31) ----
  bf16x8 qhi[2][2], qlo[2][2];
#pragma unroll
  for (int g = 0; g < 2; ++g)
#pragma unroll
    for (int ks = 0; ks < 2; ++ks) {
      const size_t a = kbase + (size_t)(q0 + w * 32 + g * 16 + fr) * D_ + ks * 32 + q * 8;
      qhi[g][ks] = *(const bf16x8*)(Qhi + a);
      qlo[g][ks] = *(const bf16x8*)(Qlo + a);
    }

  f32x4 accO[2][4] = {};
  float mrow[2][4], lrow[2][4];
#pragma unroll
  for (int g = 0; g < 2; ++g)
#pragma unroll
    for (int r = 0; r < 4; ++r) { mrow[g][r] = -1e30f; lrow[g][r] = 0.0f; }

  for (int s0 = 0; s0 < T_; s0 += 64) {
    __syncthreads(); // all waves done reading previous K/V tiles
    // ---- stage K hi/lo [64][64] and Vt hi/lo [64][64], XOR chunk swizzle ----
#pragma unroll
    for (int c = 0; c < 2; ++c) {
      const int ci = w * 128 + c * 64 + lane;   // chunk id 0..511
      const int row = ci >> 3, slot = ci & 7;
      const int kch = slot ^ (row & 7);
      const int ldsb = (w * 128 + c * 64) * 8;  // shorts
      const unsigned short* sk = Khi + kbase + (size_t)(s0 + row) * D_ + kch * 8;
      __builtin_amdgcn_global_load_lds(
          (const __attribute__((address_space(1))) void*)sk,
          (__attribute__((address_space(3))) void*)(KhiS + ldsb), 16, 0, 0);
      const unsigned short* sk2 = Klo + kbase + (size_t)(s0 + row) * D_ + kch * 8;
      __builtin_amdgcn_global_load_lds(
          (const __attribute__((address_space(1))) void*)sk2,
          (__attribute__((address_space(3))) void*)(KloS + ldsb), 16, 0, 0);
      const unsigned short* sv = Vthi + vbase + (size_t)row * T_ + s0 + kch * 8;
      __builtin_amdgcn_global_load_lds(
          (const __attribute__((address_space(1))) void*)sv,
          (__attribute__((address_space(3))) void*)(VhiS + ldsb), 16, 0, 0);
      const unsigned short* sv2 = Vtlo + vbase + (size_t)row * T_ + s0 + kch * 8;
      __builtin_amdgcn_global_load_lds(
          (const __attribute__((address_space(1))) void*)sv2,
          (__attribute__((address_space(3))) void*)(VloS + ldsb), 16, 0, 0);
    }
    __syncthreads(); // vmcnt drained by compiler before barrier

    // ---- S = Q K^T (split bf16: hi*hi + hi*lo + lo*hi) ----
    f32x4 accS[2][4] = {};
#pragma unroll
    for (int j = 0; j < 4; ++j) {
      bf16x8 khf[2], klf[2];
#pragma unroll
      for (int ks = 0; ks < 2; ++ks) {
        const int rs = j * 16 + fr;
        const int off = rs * 64 + ((ks * 4 + q) ^ (rs & 7)) * 8;
        khf[ks] = *(const bf16x8*)(KhiS + off);
        klf[ks] = *(const bf16x8*)(KloS + off);
      }
#pragma unroll
      for (int g = 0; g < 2; ++g)
#pragma unroll
        for (int ks = 0; ks < 2; ++ks) {
          accS[g][j] = __builtin_amdgcn_mfma_f32_16x16x32_bf16(qhi[g][ks], khf[ks], accS[g][j], 0, 0, 0);
          accS[g][j] = __builtin_amdgcn_mfma_f32_16x16x32_bf16(qhi[g][ks], klf[ks], accS[g][j], 0, 0, 0);
          accS[g][j] = __builtin_amdgcn_mfma_f32_16x16x32_bf16(qlo[g][ks], khf[ks], accS[g][j], 0, 0, 0);
        }
    }

    // ---- online softmax (rows owned by 16-lane groups) + P -> LDS ----
#pragma unroll
    for (int g = 0; g < 2; ++g) {
#pragma unroll
      for (int r = 0; r < 4; ++r) {
        float sv[4];
#pragma unroll
        for (int j = 0; j < 4; ++j) sv[j] = accS[g][j][r] * 0.125f;
        float mx = fmaxf(fmaxf(sv[0], sv[1]), fmaxf(sv[2], sv[3]));
#pragma unroll
        for (int off = 1; off < 16; off <<= 1)
          mx = fmaxf(mx, __shfl_xor(mx, off));
        const float newm = fmaxf(mrow[g][r], mx);
        const float corr = __expf(mrow[g][r] - newm);
        mrow[g][r] = newm;
        float rs = 0.0f;
#pragma unroll
        for (int j = 0; j < 4; ++j) {
          sv[j] = __expf(sv[j] - newm);
          rs += sv[j];
        }
#pragma unroll
        for (int off = 1; off < 16; off <<= 1) rs += __shfl_xor(rs, off);
        lrow[g][r] = lrow[g][r] * corr + rs;
#pragma unroll
        for (int j = 0; j < 4; ++j) {
          accO[g][j][r] *= corr;
          Ps[w][g * 16 + q * 4 + r][j * 16 + fr] = f2bf(sv[j]);
        }
      }
    }

    // Ps is per-wave private; ensure writes land before fragment reads.
    asm volatile("s_waitcnt lgkmcnt(0)" ::: "memory");
    __builtin_amdgcn_sched_barrier(0);

    // ---- O += P V (P bf16, V split hi+lo) ----
    bf16x8 pa[2][2];
#pragma unroll
    for (int g = 0; g < 2; ++g)
#pragma unroll
      for (int ks = 0; ks < 2; ++ks)
        pa[g][ks] = *(const bf16x8*)&Ps[w][g * 16 + fr][ks * 32 + q * 8];
#pragma unroll
    for (int j = 0; j < 4; ++j) {
      bf16x8 vh[2], vl[2];
#pragma unroll
      for (int ks = 0; ks < 2; ++ks) {
        const int rd = j * 16 + fr;
        const int off = rd * 64 + ((ks * 4 + q) ^ (rd & 7)) * 8;
        vh[ks] = *(const bf16x8*)(VhiS + off);
        vl[ks] = *(const bf16x8*)(VloS + off);
      }
#pragma unroll
      for (int g = 0; g < 2; ++g)
#pragma unroll
        for (int ks = 0; ks < 2; ++ks) {
          accO[g][j] = __builtin_amdgcn_mfma_f32_16x16x32_bf16(pa[g][ks], vh[ks], accO[g][j], 0, 0, 0);
          accO[g][j] = __builtin_amdgcn_mfma_f32_16x16x32_bf16(pa[g][ks], vl[ks], accO[g][j], 0, 0, 0);
        }
    }
  }

  // ---- epilogue: normalize, split to bf16 hi/lo ctx [b,t,h*64+d] ----
#pragma unroll
  for (int g = 0; g < 2; ++g) {
#pragma unroll
    for (int r = 0; r < 4; ++r) {
      const float inv = 1.0f / lrow[g][r];
      const int t = q0 + w * 32 + g * 16 + q * 4 + r;
#pragma unroll
      for (int j = 0; j < 4; ++j) {
        const float v = accO[g][j][r] * inv;
        const unsigned short hv = f2bf(v);
        const unsigned short lv = f2bf(v - bf2f(hv));
        const size_t idx = ((size_t)b * T_ + t) * C_ + h * D_ + j * 16 + fr;
        chi[idx] = hv;
        clo[idx] = lv;
      }
    }
  }
}

// ---------------------------------------------------------------------------
extern "C" void kernel_launch(void* const* d_in, const int* in_sizes, int n_in,
                              void* d_out, int out_size, void* d_ws,
                              size_t ws_size, hipStream_t stream) {
  const float* x = (const float*)d_in[0];
  const float* Wq = (const float*)d_in[1];
  const float* bq = (const float*)d_in[2];
  const float* Wk = (const float*)d_in[3];
  const float* bk = (const float*)d_in[4];
  const float* Wv = (const float*)d_in[5];
  const float* bv = (const float*)d_in[6];
  const float* Wp = (const float*)d_in[7];
  const float* bp = (const float*)d_in[8];
  float* out = (float*)d_out;

  char* w = (char*)d_ws;
  unsigned short* xhi = (unsigned short*)w;     w += (size_t)M_ * C_ * 2;
  unsigned short* xlo = (unsigned short*)w;     w += (size_t)M_ * C_ * 2;
  unsigned short* Wqkv_hi = (unsigned short*)w; w += (size_t)3 * C_ * C_ * 2;
  unsigned short* Wqkv_lo = (unsigned short*)w; w += (size_t)3 * C_ * C_ * 2;
  unsigned short* Wp_hi = (unsigned short*)w;   w += (size_t)C_ * C_ * 2;
  unsigned short* Wp_lo = (unsigned short*)w;   w += (size_t)C_ * C_ * 2;
  unsigned short* Qhi = (unsigned short*)w;     w += (size_t)M_ * C_ * 2;
  unsigned short* Qlo = (unsigned short*)w;     w += (size_t)M_ * C_ * 2;
  unsigned short* Khi = (unsigned short*)w;     w += (size_t)M_ * C_ * 2;
  unsigned short* Klo = (unsigned short*)w;     w += (size_t)M_ * C_ * 2;
  unsigned short* Vthi = (unsigned short*)w;    w += (size_t)M_ * C_ * 2;
  unsigned short* Vtlo = (unsigned short*)w;    w += (size_t)M_ * C_ * 2;
  unsigned short* chi = (unsigned short*)w;     w += (size_t)M_ * C_ * 2;
  unsigned short* clo = (unsigned short*)w;     w += (size_t)M_ * C_ * 2;

  const dim3 blk(256);

  conv_x<<<dim3((M_ * C_) / (4 * 256)), blk, 0, stream>>>(x, xhi, xlo);
  conv_wT<<<dim3(16, 16), blk, 0, stream>>>(Wq, Wqkv_hi, Wqkv_lo, 0);
  conv_wT<<<dim3(16, 16), blk, 0, stream>>>(Wk, Wqkv_hi, Wqkv_lo, 1024);
  conv_wT<<<dim3(16, 16), blk, 0, stream>>>(Wv, Wqkv_hi, Wqkv_lo, 2048);
  conv_wT<<<dim3(16, 16), blk, 0, stream>>>(Wp, Wp_hi, Wp_lo, 0);

  // fused QKV projection -> split Q,K [b,h,t,d] and transposed split V [b,h,d,t]
  gemm_mfma<1><<<dim3(3072 / 128, M_ / 128), blk, 0, stream>>>(
      xhi, xlo, Wqkv_hi, Wqkv_lo, bq, bk, bv,
      Qhi, Qlo, Khi, Klo, Vthi, Vtlo);

  flash_mfma<<<dim3(T_ / 128, B_ * H_), blk, 0, stream>>>(
      Qhi, Qlo, Khi, Klo, Vthi, Vtlo, chi, clo);

  // output projection
  gemm_mfma<0><<<dim3(1024 / 128, M_ / 128), blk, 0, stream>>>(
      chi, clo, Wp_hi, Wp_lo, bp, bp, bp,
      out, nullptr, nullptr, nullptr, nullptr, nullptr);

  (void)in_sizes; (void)n_in; (void)out_size; (void)ws_size;
}